// Round 4
// baseline (566.408 us; speedup 1.0000x reference)
//
#include <hip/hip_runtime.h>
#include <hip/hip_bf16.h>

#define NV 2708
#define INC 1433
#define PSTR 2720     // padded row length (mult of 32 bf16; 16B-aligned b128 frags)
#define NROWPAD 2720  // padded row count for K16/F16 so fragment reads never leave d_ws

typedef __attribute__((ext_vector_type(8))) short bf16x8;
typedef __attribute__((ext_vector_type(4))) float f32x4;

__device__ __forceinline__ float bf2f(unsigned short u){
  union { unsigned int i; float f; } v; v.i = ((unsigned int)u) << 16; return v.f;
}
__device__ __forceinline__ unsigned short f2bf(float f){
  union { float f; unsigned int i; } v; v.f = f;
  return (unsigned short)((v.i + 0x7fffu + ((v.i >> 16) & 1u)) >> 16);  // RNE
}

// ---------------- projections: K = X Wk^T ; Q^T ; V^T (padded) ----------------
// fp32 inputs, converted to bf16 at stage time. grid (170,1,3).
__global__ __launch_bounds__(256) void proj16(
    const float* __restrict__ X,
    const float* __restrict__ W0, const float* __restrict__ W1,
    const float* __restrict__ W2,
    unsigned short* __restrict__ K16, unsigned short* __restrict__ QT16,
    unsigned short* __restrict__ VT16)
{
  __shared__ __align__(16) unsigned short At[16*72];
  __shared__ __align__(16) unsigned short Bt[64*72];
  const int tid  = threadIdx.x;
  const int lane = tid & 63, wave = tid >> 6;
  const int quad = lane >> 4, lr = lane & 15;
  const int m0 = blockIdx.x * 16;
  const int z  = blockIdx.z;
  const float* W = (z==0) ? W0 : (z==1) ? W1 : W2;

  f32x4 acc = {};
  for (int k0 = 0; k0 < INC; k0 += 64){
    { // A: 16x64 tile of X (fp32 -> bf16)
      int r = tid >> 4, cb = (tid & 15) * 4;
      #pragma unroll
      for (int e = 0; e < 4; e++){
        int c = cb + e, kk = k0 + c;
        unsigned short v = 0;
        if (kk < INC && (m0 + r) < NV) v = f2bf(X[(size_t)(m0+r)*INC + kk]);
        At[r*72 + c] = v;
      }
    }
    { // B: 64x64 tile of W (fp32 -> bf16)
      int n = tid >> 2, g = tid & 3;
      #pragma unroll
      for (int i = 0; i < 16; i++){
        int c = g*16 + i, kk = k0 + c;
        unsigned short v = 0;
        if (kk < INC) v = f2bf(W[(size_t)n*INC + kk]);
        Bt[n*72 + c] = v;
      }
    }
    __syncthreads();
    #pragma unroll
    for (int ks = 0; ks < 2; ks++){
      bf16x8 af = *(const bf16x8*)&At[lr*72 + ks*32 + quad*8];
      bf16x8 bv = *(const bf16x8*)&Bt[(wave*16 + lr)*72 + ks*32 + quad*8];
      acc = __builtin_amdgcn_mfma_f32_16x16x32_bf16(af, bv, acc, 0, 0, 0);
    }
    __syncthreads();
  }
  #pragma unroll
  for (int r = 0; r < 4; r++){
    int row = m0 + quad*4 + r;
    int col = wave*16 + lr;
    if (row < NV){
      unsigned short h = f2bf(acc[r]);
      if (z == 0)      K16 [(size_t)row*64   + col] = h;
      else if (z == 1) QT16[(size_t)col*NV   + row] = h;
      else             VT16[(size_t)col*PSTR + row] = h;
    }
  }
}

// ---------------- spectral GEMMs ----------------
// C[m][n] = sum_k A'(m,k) * Bg[n*ldb + k], n in [0,64). A = U (fp32).
// TRANSA: A'(m,k) = Ag[k*lda + m]; else Ag[m*lda + k].
// TROUT: O[col*ldc+row] else O[row*ldc+col]. lm!=null: scale by lmbd[row]/64.
template<int TRANSA, int TROUT>
__global__ __launch_bounds__(256) void spect16(
    const float* __restrict__ Ag, int lda, int M, int Kd,
    const unsigned short* __restrict__ Bg, int ldb,
    unsigned short* __restrict__ Og, int ldc,
    const float* __restrict__ lm)
{
  __shared__ __align__(16) unsigned short At[16*72];
  __shared__ __align__(16) unsigned short Bt[64*72];
  const int tid  = threadIdx.x;
  const int lane = tid & 63, wave = tid >> 6;
  const int quad = lane >> 4, lr = lane & 15;
  const int m0 = blockIdx.x * 16;

  f32x4 acc = {};
  for (int k0 = 0; k0 < Kd; k0 += 64){
    if (TRANSA){
      int r = tid & 15, cb = (tid >> 4) * 4;
      #pragma unroll
      for (int e = 0; e < 4; e++){
        int c = cb + e, kk = k0 + c;
        unsigned short v = 0;
        if (kk < Kd && (m0 + r) < M) v = f2bf(Ag[(size_t)kk*lda + m0 + r]);
        At[r*72 + c] = v;
      }
    } else {
      int r = tid >> 4, cb = (tid & 15) * 4;
      #pragma unroll
      for (int e = 0; e < 4; e++){
        int c = cb + e, kk = k0 + c;
        unsigned short v = 0;
        if (kk < Kd && (m0 + r) < M) v = f2bf(Ag[(size_t)(m0+r)*lda + kk]);
        At[r*72 + c] = v;
      }
    }
    {
      int n = tid >> 2, g = tid & 3;
      #pragma unroll
      for (int i = 0; i < 16; i++){
        int c = g*16 + i, kk = k0 + c;
        unsigned short v = 0;
        if (kk < Kd) v = Bg[(size_t)n*ldb + kk];
        Bt[n*72 + c] = v;
      }
    }
    __syncthreads();
    #pragma unroll
    for (int ks = 0; ks < 2; ks++){
      bf16x8 af = *(const bf16x8*)&At[lr*72 + ks*32 + quad*8];
      bf16x8 bv = *(const bf16x8*)&Bt[(wave*16 + lr)*72 + ks*32 + quad*8];
      acc = __builtin_amdgcn_mfma_f32_16x16x32_bf16(af, bv, acc, 0, 0, 0);
    }
    __syncthreads();
  }
  #pragma unroll
  for (int r = 0; r < 4; r++){
    int row = m0 + quad*4 + r;
    int col = wave*16 + lr;
    if (row < M){
      float v = acc[r];
      if (lm) v *= lm[row] * (1.0f/64.0f);
      size_t idx = TROUT ? ((size_t)col*ldc + row) : ((size_t)row*ldc + col);
      Og[idx] = f2bf(v);
    }
  }
}

// ---------------- fused |F K^T| -> masked softmax -> P V ----------------
__device__ __forceinline__ float blockReduceMax(float v, float* red){
  #pragma unroll
  for (int o = 32; o; o >>= 1) v = fmaxf(v, __shfl_xor(v, o, 64));
  __syncthreads();
  if ((threadIdx.x & 63) == 0) red[threadIdx.x >> 6] = v;
  __syncthreads();
  return fmaxf(fmaxf(red[0], red[1]), fmaxf(red[2], red[3]));
}
__device__ __forceinline__ float blockReduceSum(float v, float* red){
  #pragma unroll
  for (int o = 32; o; o >>= 1) v += __shfl_xor(v, o, 64);
  __syncthreads();
  if ((threadIdx.x & 63) == 0) red[threadIdx.x >> 6] = v;
  __syncthreads();
  return red[0] + red[1] + red[2] + red[3];
}

__global__ __launch_bounds__(256) void fused_attn(
    const unsigned short* __restrict__ F16, const unsigned short* __restrict__ K16,
    const int* __restrict__ Amask, const unsigned short* __restrict__ VT,
    float* __restrict__ Hout)   // fp32 output per reference dtype
{
  __shared__ __align__(16) unsigned short pbuf[8*PSTR];
  __shared__ float red[4];
  __shared__ float rinv[8];
  const int tid  = threadIdx.x;
  const int lane = tid & 63, wave = tid >> 6;
  const int quad = lane >> 4, lr = lane & 15;
  const int i0 = blockIdx.x * 8;
  const int NT = (NV + 15) / 16;   // 170

  // ---- phase A: S-rows = F[i0..i0+7] @ K^T, |S| -> pbuf (bf16) ----
  const unsigned short* frow = F16 + (size_t)(i0 + (lr & 7))*64;  // rows padded to NROWPAD
  bf16x8 af0 = *(const bf16x8*)(frow + quad*8);
  bf16x8 af1 = *(const bf16x8*)(frow + 32 + quad*8);
  for (int t = wave; t < NT; t += 4){
    int n0 = t*16;
    const unsigned short* krow = K16 + (size_t)(n0 + lr)*64;      // rows padded
    bf16x8 b0 = *(const bf16x8*)(krow + quad*8);
    bf16x8 b1 = *(const bf16x8*)(krow + 32 + quad*8);
    f32x4 s = {};
    s = __builtin_amdgcn_mfma_f32_16x16x32_bf16(af0, b0, s, 0, 0, 0);
    s = __builtin_amdgcn_mfma_f32_16x16x32_bf16(af1, b1, s, 0, 0, 0);
    if (quad < 2){                      // D rows 0..7 are the real ones
      int col = n0 + lr;
      if (col < NV){
        #pragma unroll
        for (int r = 0; r < 4; r++)
          pbuf[(size_t)(quad*4 + r)*PSTR + col] = f2bf(fabsf(s[r]));
      }
    }
  }
  __syncthreads();

  if (tid < PSTR - NV){                 // zero pad cols 2708..2719
    #pragma unroll
    for (int rr = 0; rr < 8; rr++) pbuf[rr*PSTR + NV + tid] = 0;
  }

  // ---- phase B: masked softmax per row (probs stay unnormalized, bf16) ----
  for (int rr = 0; rr < 8; rr++){
    const int i = i0 + rr;
    float ev[11]; int mk[11];
    float mx = -1e30f;
    if (i < NV){
      const int* arow = Amask + (size_t)i*NV;
      #pragma unroll
      for (int s = 0; s < 11; s++){
        int j = tid + s*256;
        float e = 0.f; int a = 0;
        if (j < NV){ e = bf2f(pbuf[rr*PSTR + j]); a = arow[j]; }
        ev[s] = e; mk[s] = a;
        if (a) mx = fmaxf(mx, e);
      }
    } else {
      #pragma unroll
      for (int s = 0; s < 11; s++){ ev[s] = 0.f; mk[s] = 0; }
    }
    mx = blockReduceMax(mx, red);
    float sum = 0.f;
    #pragma unroll
    for (int s = 0; s < 11; s++){
      int j = tid + s*256;
      if (j < NV){
        float p = 0.f;
        if (i < NV && mk[s]) p = __expf(ev[s] - mx);
        sum += p;
        pbuf[rr*PSTR + j] = f2bf(p);
      }
    }
    sum = blockReduceSum(sum, red);
    if (tid == 0) rinv[rr] = (sum > 0.f) ? (1.f/sum) : 0.f;
  }
  __syncthreads();

  // ---- phase C: H = (P V) * rinv ----
  const int c0 = wave * 16;
  const int mr = lr & 7;                // alias rows 8..15 -> 0..7
  f32x4 acc = {0.f, 0.f, 0.f, 0.f};
  for (int k0 = 0; k0 < NV; k0 += 32){
    bf16x8 af = *(const bf16x8*)&pbuf[(size_t)mr*PSTR + k0 + quad*8];
    bf16x8 bv = *(const bf16x8*)&VT[(size_t)(c0 + lr)*PSTR + k0 + quad*8];
    acc = __builtin_amdgcn_mfma_f32_16x16x32_bf16(af, bv, acc, 0, 0, 0);
  }
  #pragma unroll
  for (int r = 0; r < 4; r++){
    int row = quad*4 + r;
    if (row < 8){
      int i = i0 + row;
      if (i < NV) Hout[(size_t)i*64 + c0 + lr] = acc[r] * rinv[row];
    }
  }
}

extern "C" void kernel_launch(void* const* d_in, const int* in_sizes, int n_in,
                              void* d_out, int out_size, void* d_ws, size_t ws_size,
                              hipStream_t stream){
  (void)in_sizes; (void)n_in; (void)out_size; (void)ws_size;
  const float* X  = (const float*)d_in[0];   // fp32 per reference dtypes
  const int*   A  = (const int*)d_in[1];
  const float* U  = (const float*)d_in[2];
  const float* WK = (const float*)d_in[3];
  const float* WQ = (const float*)d_in[4];
  const float* WV = (const float*)d_in[5];
  const float* lm = (const float*)d_in[6];

  // tiny workspace: 5 bf16 buffers, ~1.74 MB total
  char* ws = (char*)d_ws;
  size_t off = 0;
  auto alloc = [&](size_t bytes){ size_t o = off; off = (off + bytes + 255) & ~(size_t)255; return o; };
  unsigned short* K16  = (unsigned short*)(ws + alloc((size_t)NROWPAD*64*2));  // [row][c], rows padded
  unsigned short* QT16 = (unsigned short*)(ws + alloc((size_t)64*NV*2));       // [c][row]
  unsigned short* G2T  = (unsigned short*)(ws + alloc((size_t)64*NV*2));       // [c][row]
  unsigned short* VT16 = (unsigned short*)(ws + alloc((size_t)64*PSTR*2));     // [c][row], cols padded
  unsigned short* F16  = (unsigned short*)(ws + alloc((size_t)NROWPAD*64*2));  // [row][c], rows padded

  const int MT16 = (NV + 15) / 16;   // 170

  // K = X Wk^T ; Q^T ; V^T
  proj16<<<dim3(MT16, 1, 3), 256, 0, stream>>>(X, WK, WQ, WV, K16, QT16, VT16);
  // G2^T[c][m] = (U^T Q)[m][c] * lmbd[m]/64
  spect16<1,1><<<dim3(MT16), 256, 0, stream>>>(U, NV, NV, NV, QT16, NV, G2T, NV, lm);
  // F[m][c] = (U G2)[m][c]
  spect16<0,0><<<dim3(MT16), 256, 0, stream>>>(U, NV, NV, NV, G2T, NV, F16, 64, (const float*)nullptr);
  // fused |F K^T| -> masked softmax -> P V  (fp32 out)
  fused_attn<<<dim3((NV + 7)/8), 256, 0, stream>>>(F16, K16, A, VT16, (float*)d_out);
}

// Round 5
// 261.324 us; speedup vs baseline: 2.1675x; 2.1675x over previous
//
#include <hip/hip_runtime.h>

#define NV 2708
#define INC 1433
#define PSTR 2720          // padded row len for K16/VT16/F16 (mult of 32)
#define BSTR 2752          // padded row len for QT16/G2T16 (mult of 64)
#define SLAB ((size_t)(2752*64))

typedef __attribute__((ext_vector_type(8))) short bf16x8;
typedef __attribute__((ext_vector_type(4))) float f32x4;
typedef __attribute__((ext_vector_type(4))) unsigned short u16x4;

__device__ __forceinline__ float bf2f(unsigned short u){
  union { unsigned int i; float f; } v; v.i = ((unsigned int)u) << 16; return v.f;
}
__device__ __forceinline__ unsigned short f2bf(float f){
  union { float f; unsigned int i; } v; v.f = f;
  return (unsigned short)((v.i + 0x7fffu + ((v.i >> 16) & 1u)) >> 16);  // RNE
}

// =============== proj: partials of {K,Q,V} = X @ W^T, split-K ===============
// grid (43, 5, 3): 64-row M-tile, 5 K-chunks of 320, z = weight select.
__global__ __launch_bounds__(256) void proj(
    const float* __restrict__ X, const float* __restrict__ W0,
    const float* __restrict__ W1, const float* __restrict__ W2,
    float* __restrict__ part)
{
  __shared__ __align__(16) unsigned short At[64*72];
  __shared__ __align__(16) unsigned short Bt[64*72];
  const int tid = threadIdx.x;
  const int lane = tid & 63, wave = tid >> 6, quad = lane >> 4, lr = lane & 15;
  const int m0 = blockIdx.x * 64;
  const int s  = blockIdx.y, z = blockIdx.z;
  const float* W = (z==0) ? W0 : (z==1) ? W1 : W2;
  const int kbeg = s * 320, kend = min(kbeg + 320, INC);
  const int wm = (wave & 1) * 32, wn = (wave >> 1) * 32;
  f32x4 acc[2][2] = {};

  const int r = tid >> 2, cg = tid & 3;
  const bool rowok = (m0 + r) < NV;
  const float* xrow = X + (size_t)min(m0 + r, NV-1) * INC;
  const float* wrow = W + (size_t)r * INC;

  for (int k0 = kbeg; k0 < kend; k0 += 64){
    {
      unsigned short ta[16], tb[16];
      #pragma unroll
      for (int e = 0; e < 16; e++){
        int kk = k0 + cg*16 + e;
        bool ok = kk < kend;
        ta[e] = (ok && rowok) ? f2bf(xrow[kk]) : (unsigned short)0;
        tb[e] = ok ? f2bf(wrow[kk]) : (unsigned short)0;
      }
      *(bf16x8*)&At[r*72 + cg*16]     = *(bf16x8*)&ta[0];
      *(bf16x8*)&At[r*72 + cg*16 + 8] = *(bf16x8*)&ta[8];
      *(bf16x8*)&Bt[r*72 + cg*16]     = *(bf16x8*)&tb[0];
      *(bf16x8*)&Bt[r*72 + cg*16 + 8] = *(bf16x8*)&tb[8];
    }
    __syncthreads();
    #pragma unroll
    for (int ks = 0; ks < 2; ks++){
      bf16x8 af[2], bv[2];
      #pragma unroll
      for (int t = 0; t < 2; t++){
        af[t] = *(const bf16x8*)&At[(wm + t*16 + lr)*72 + ks*32 + quad*8];
        bv[t] = *(const bf16x8*)&Bt[(wn + t*16 + lr)*72 + ks*32 + quad*8];
      }
      #pragma unroll
      for (int tm = 0; tm < 2; tm++)
        #pragma unroll
        for (int tn = 0; tn < 2; tn++)
          acc[tm][tn] = __builtin_amdgcn_mfma_f32_16x16x32_bf16(af[tm], bv[tn], acc[tm][tn], 0, 0, 0);
    }
    __syncthreads();
  }
  float* dst = part + (size_t)(z*5 + s) * SLAB;
  #pragma unroll
  for (int tm = 0; tm < 2; tm++)
    #pragma unroll
    for (int tn = 0; tn < 2; tn++)
      #pragma unroll
      for (int e = 0; e < 4; e++)
        dst[(size_t)(m0 + wm + tm*16 + quad*4 + e)*64 + wn + tn*16 + lr] = acc[tm][tn][e];
}

// K16[m][c] ; QT16[c][m] ; VT16[c][m]  (+zero pads). grid (688, 3).
__global__ __launch_bounds__(256) void reduce_proj(
    const float* __restrict__ part, unsigned short* __restrict__ K16,
    unsigned short* __restrict__ QT16, unsigned short* __restrict__ VT16)
{
  int idx = blockIdx.x*256 + threadIdx.x;       // < 2752*64
  int z = blockIdx.y;
  int m = idx >> 6, c = idx & 63;
  const float* base = part + (size_t)z*5*SLAB + idx;
  float v = 0.f;
  #pragma unroll
  for (int s = 0; s < 5; s++) v += base[s*SLAB];
  unsigned short h = (m < NV) ? f2bf(v) : (unsigned short)0;
  if (z == 0){ if (m < PSTR) K16[(size_t)m*64 + c] = h; }
  else if (z == 1){ QT16[(size_t)c*BSTR + m] = h; }
  else { if (m < PSTR) VT16[(size_t)c*PSTR + m] = h; }
}

// =============== gemmG: partials of G = U^T @ Q  (A staged-transposed) ======
// grid (43, 15): K-chunks of 192.
__global__ __launch_bounds__(256) void gemmG(
    const float* __restrict__ U, const unsigned short* __restrict__ QT,
    float* __restrict__ part)
{
  __shared__ __align__(16) unsigned short At[64*72];
  __shared__ __align__(16) unsigned short Bt[64*72];
  const int tid = threadIdx.x;
  const int lane = tid & 63, wave = tid >> 6, quad = lane >> 4, lr = lane & 15;
  const int m0 = blockIdx.x * 64;
  const int s  = blockIdx.y;
  const int kbeg = s * 192, kend = min(kbeg + 192, NV);
  const int wm = (wave & 1) * 32, wn = (wave >> 1) * 32;
  f32x4 acc[2][2] = {};

  const int mg = (tid >> 4) * 4;                 // m-local group of 4
  const bool mok = (m0 + mg) < NV;               // 4-aligned vs NV%4==0
  const int bn = tid >> 2, bcg = tid & 3;

  for (int k0 = kbeg; k0 < kend; k0 += 64){
    #pragma unroll
    for (int p = 0; p < 4; p++){
      int kr = (tid & 15) + p*16;
      int krow = k0 + kr;
      float4 v = make_float4(0.f,0.f,0.f,0.f);
      if (krow < NV && mok) v = *(const float4*)(U + (size_t)krow*NV + m0 + mg);
      At[(mg+0)*72 + kr] = f2bf(v.x);
      At[(mg+1)*72 + kr] = f2bf(v.y);
      At[(mg+2)*72 + kr] = f2bf(v.z);
      At[(mg+3)*72 + kr] = f2bf(v.w);
    }
    {
      const unsigned short* qrow = QT + (size_t)bn*BSTR + k0 + bcg*16;
      *(bf16x8*)&Bt[bn*72 + bcg*16]     = *(const bf16x8*)(qrow);
      *(bf16x8*)&Bt[bn*72 + bcg*16 + 8] = *(const bf16x8*)(qrow + 8);
    }
    __syncthreads();
    #pragma unroll
    for (int ks = 0; ks < 2; ks++){
      bf16x8 af[2], bv[2];
      #pragma unroll
      for (int t = 0; t < 2; t++){
        af[t] = *(const bf16x8*)&At[(wm + t*16 + lr)*72 + ks*32 + quad*8];
        bv[t] = *(const bf16x8*)&Bt[(wn + t*16 + lr)*72 + ks*32 + quad*8];
      }
      #pragma unroll
      for (int tm = 0; tm < 2; tm++)
        #pragma unroll
        for (int tn = 0; tn < 2; tn++)
          acc[tm][tn] = __builtin_amdgcn_mfma_f32_16x16x32_bf16(af[tm], bv[tn], acc[tm][tn], 0, 0, 0);
    }
    __syncthreads();
  }
  float* dst = part + (size_t)s * SLAB;
  #pragma unroll
  for (int tm = 0; tm < 2; tm++)
    #pragma unroll
    for (int tn = 0; tn < 2; tn++)
      #pragma unroll
      for (int e = 0; e < 4; e++)
        dst[(size_t)(m0 + wm + tm*16 + quad*4 + e)*64 + wn + tn*16 + lr] = acc[tm][tn][e];
}

// G2T16[c][m] = bf16(G[m][c] * lmbd[m]/64), zero pads. grid 688.
__global__ __launch_bounds__(256) void reduce_g(
    const float* __restrict__ part, const float* __restrict__ lm,
    unsigned short* __restrict__ G2T)
{
  int idx = blockIdx.x*256 + threadIdx.x;
  int m = idx >> 6, c = idx & 63;
  const float* base = part + idx;
  float v = 0.f;
  #pragma unroll
  for (int s = 0; s < 15; s++) v += base[s*SLAB];
  unsigned short h = 0;
  if (m < NV) h = f2bf(v * lm[m] * (1.0f/64.0f));
  G2T[(size_t)c*BSTR + m] = h;
}

// =============== gemmF: partials of F = U @ G2 ==============================
__global__ __launch_bounds__(256) void gemmF(
    const float* __restrict__ U, const unsigned short* __restrict__ G2T,
    float* __restrict__ part)
{
  __shared__ __align__(16) unsigned short At[64*72];
  __shared__ __align__(16) unsigned short Bt[64*72];
  const int tid = threadIdx.x;
  const int lane = tid & 63, wave = tid >> 6, quad = lane >> 4, lr = lane & 15;
  const int m0 = blockIdx.x * 64;
  const int s  = blockIdx.y;
  const int kbeg = s * 192, kend = min(kbeg + 192, NV);
  const int wm = (wave & 1) * 32, wn = (wave >> 1) * 32;
  f32x4 acc[2][2] = {};

  const int r = tid >> 2, cg = tid & 3;
  const bool rowok = (m0 + r) < NV;
  const float* urow = U + (size_t)min(m0 + r, NV-1) * NV;

  for (int k0 = kbeg; k0 < kend; k0 += 64){
    #pragma unroll
    for (int h = 0; h < 2; h++){
      int kk = k0 + cg*16 + h*8;
      float4 a = make_float4(0.f,0.f,0.f,0.f), b = make_float4(0.f,0.f,0.f,0.f);
      if (rowok && kk < NV)     a = *(const float4*)(urow + kk);
      if (rowok && kk + 4 < NV) b = *(const float4*)(urow + kk + 4);
      unsigned short t8[8] = { f2bf(a.x), f2bf(a.y), f2bf(a.z), f2bf(a.w),
                               f2bf(b.x), f2bf(b.y), f2bf(b.z), f2bf(b.w) };
      *(bf16x8*)&At[r*72 + cg*16 + h*8] = *(bf16x8*)t8;
    }
    {
      const unsigned short* grow = G2T + (size_t)r*BSTR + k0 + cg*16;
      *(bf16x8*)&Bt[r*72 + cg*16]     = *(const bf16x8*)(grow);
      *(bf16x8*)&Bt[r*72 + cg*16 + 8] = *(const bf16x8*)(grow + 8);
    }
    __syncthreads();
    #pragma unroll
    for (int ks = 0; ks < 2; ks++){
      bf16x8 af[2], bv[2];
      #pragma unroll
      for (int t = 0; t < 2; t++){
        af[t] = *(const bf16x8*)&At[(wm + t*16 + lr)*72 + ks*32 + quad*8];
        bv[t] = *(const bf16x8*)&Bt[(wn + t*16 + lr)*72 + ks*32 + quad*8];
      }
      #pragma unroll
      for (int tm = 0; tm < 2; tm++)
        #pragma unroll
        for (int tn = 0; tn < 2; tn++)
          acc[tm][tn] = __builtin_amdgcn_mfma_f32_16x16x32_bf16(af[tm], bv[tn], acc[tm][tn], 0, 0, 0);
    }
    __syncthreads();
  }
  float* dst = part + (size_t)s * SLAB;
  #pragma unroll
  for (int tm = 0; tm < 2; tm++)
    #pragma unroll
    for (int tn = 0; tn < 2; tn++)
      #pragma unroll
      for (int e = 0; e < 4; e++)
        dst[(size_t)(m0 + wm + tm*16 + quad*4 + e)*64 + wn + tn*16 + lr] = acc[tm][tn][e];
}

// F16[m][c] (rows padded to 2720, pads zero). grid 680.
__global__ __launch_bounds__(256) void reduce_f(
    const float* __restrict__ part, unsigned short* __restrict__ F16)
{
  int idx = blockIdx.x*256 + threadIdx.x;       // < 2720*64
  int m = idx >> 6, c = idx & 63;
  const float* base = part + (size_t)m*64 + c;
  float v = 0.f;
  #pragma unroll
  for (int s = 0; s < 15; s++) v += base[s*SLAB];
  F16[(size_t)m*64 + c] = (m < NV) ? f2bf(v) : (unsigned short)0;
}

// =============== fused |F K^T| -> masked softmax -> P V =====================
__device__ __forceinline__ float blockReduceMax(float v, float* red){
  #pragma unroll
  for (int o = 32; o; o >>= 1) v = fmaxf(v, __shfl_xor(v, o, 64));
  __syncthreads();
  if ((threadIdx.x & 63) == 0) red[threadIdx.x >> 6] = v;
  __syncthreads();
  return fmaxf(fmaxf(red[0], red[1]), fmaxf(red[2], red[3]));
}
__device__ __forceinline__ float blockReduceSum(float v, float* red){
  #pragma unroll
  for (int o = 32; o; o >>= 1) v += __shfl_xor(v, o, 64);
  __syncthreads();
  if ((threadIdx.x & 63) == 0) red[threadIdx.x >> 6] = v;
  __syncthreads();
  return red[0] + red[1] + red[2] + red[3];
}

__global__ __launch_bounds__(256) void fused_attn(
    const unsigned short* __restrict__ F16, const unsigned short* __restrict__ K16,
    const int* __restrict__ Amask, const unsigned short* __restrict__ VT,
    float* __restrict__ Hout)
{
  __shared__ __align__(16) unsigned short pbuf[8*PSTR];
  __shared__ float red[4];
  __shared__ float rinv[8];
  const int tid  = threadIdx.x;
  const int lane = tid & 63, wave = tid >> 6;
  const int quad = lane >> 4, lr = lane & 15;
  const int i0 = blockIdx.x * 8;
  const int NT = (NV + 15) / 16;   // 170

  // ---- phase A: |F K^T| rows -> pbuf (bf16) ----
  const unsigned short* frow = F16 + (size_t)(i0 + (lr & 7))*64;
  bf16x8 af0 = *(const bf16x8*)(frow + quad*8);
  bf16x8 af1 = *(const bf16x8*)(frow + 32 + quad*8);
  for (int t = wave; t < NT; t += 4){
    int n0 = t*16;
    const unsigned short* krow = K16 + (size_t)(n0 + lr)*64;
    bf16x8 b0 = *(const bf16x8*)(krow + quad*8);
    bf16x8 b1 = *(const bf16x8*)(krow + 32 + quad*8);
    f32x4 sv = {};
    sv = __builtin_amdgcn_mfma_f32_16x16x32_bf16(af0, b0, sv, 0, 0, 0);
    sv = __builtin_amdgcn_mfma_f32_16x16x32_bf16(af1, b1, sv, 0, 0, 0);
    if (quad < 2){
      int col = n0 + lr;
      if (col < NV){
        #pragma unroll
        for (int e = 0; e < 4; e++)
          pbuf[(size_t)(quad*4 + e)*PSTR + col] = f2bf(fabsf(sv[e]));
      }
    }
  }
  __syncthreads();

  if (tid < PSTR - NV){
    #pragma unroll
    for (int rr = 0; rr < 8; rr++) pbuf[rr*PSTR + NV + tid] = 0;
  }

  // ---- phase B: masked softmax per row (int4 mask, ushort4 pbuf) ----
  for (int rr = 0; rr < 8; rr++){
    const int i = i0 + rr;
    float ev[12]; int mk[12];
    float mx = -1e30f;
    if (i < NV){
      const int4* arow = (const int4*)(Amask + (size_t)i*NV);
      #pragma unroll
      for (int s = 0; s < 3; s++){
        int c = tid + s*256;
        int4 a = {0,0,0,0};
        u16x4 e4 = {0,0,0,0};
        if (c < NV/4){ a = arow[c]; e4 = *(const u16x4*)&pbuf[rr*PSTR + 4*c]; }
        mk[s*4+0] = a.x; mk[s*4+1] = a.y; mk[s*4+2] = a.z; mk[s*4+3] = a.w;
        #pragma unroll
        for (int e = 0; e < 4; e++){
          ev[s*4+e] = bf2f(e4[e]);
          if (mk[s*4+e]) mx = fmaxf(mx, ev[s*4+e]);
        }
      }
    } else {
      #pragma unroll
      for (int q = 0; q < 12; q++){ ev[q] = 0.f; mk[q] = 0; }
    }
    mx = blockReduceMax(mx, red);
    float sum = 0.f;
    #pragma unroll
    for (int s = 0; s < 3; s++){
      int c = tid + s*256;
      if (c < NV/4){
        u16x4 pw;
        #pragma unroll
        for (int e = 0; e < 4; e++){
          float p = 0.f;
          if (i < NV && mk[s*4+e]) p = __expf(ev[s*4+e] - mx);
          sum += p;
          pw[e] = f2bf(p);
        }
        *(u16x4*)&pbuf[rr*PSTR + 4*c] = pw;
      }
    }
    sum = blockReduceSum(sum, red);
    if (tid == 0) rinv[rr] = (sum > 0.f) ? (1.f/sum) : 0.f;
  }
  __syncthreads();

  // ---- phase C: H = (P V) * rinv ----
  const int c0 = wave * 16;
  const int mr = lr & 7;
  f32x4 acc = {0.f, 0.f, 0.f, 0.f};
  for (int k0 = 0; k0 < NV; k0 += 32){
    bf16x8 af = *(const bf16x8*)&pbuf[(size_t)mr*PSTR + k0 + quad*8];
    bf16x8 bv = *(const bf16x8*)&VT[(size_t)(c0 + lr)*PSTR + k0 + quad*8];
    acc = __builtin_amdgcn_mfma_f32_16x16x32_bf16(af, bv, acc, 0, 0, 0);
  }
  #pragma unroll
  for (int e = 0; e < 4; e++){
    int row = quad*4 + e;
    if (row < 8){
      int i = i0 + row;
      if (i < NV) Hout[(size_t)i*64 + c0 + lr] = acc[e] * rinv[row];
    }
  }
}

extern "C" void kernel_launch(void* const* d_in, const int* in_sizes, int n_in,
                              void* d_out, int out_size, void* d_ws, size_t ws_size,
                              hipStream_t stream){
  (void)in_sizes; (void)n_in; (void)out_size; (void)ws_size;
  const float* X  = (const float*)d_in[0];
  const int*   A  = (const int*)d_in[1];
  const float* U  = (const float*)d_in[2];
  const float* WK = (const float*)d_in[3];
  const float* WQ = (const float*)d_in[4];
  const float* WV = (const float*)d_in[5];
  const float* lm = (const float*)d_in[6];

  char* ws = (char*)d_ws;
  size_t off = 0;
  auto alloc = [&](size_t bytes){ size_t o = off; off = (off + bytes + 255) & ~(size_t)255; return o; };
  float*          part = (float*)(ws + alloc(15*SLAB*4));                   // 10.6 MB, reused 3x
  unsigned short* K16  = (unsigned short*)(ws + alloc((size_t)PSTR*64*2));  // [m][c]
  unsigned short* QT16 = (unsigned short*)(ws + alloc((size_t)64*BSTR*2));  // [c][m]
  unsigned short* G2T  = (unsigned short*)(ws + alloc((size_t)64*BSTR*2));  // [c][m]
  unsigned short* VT16 = (unsigned short*)(ws + alloc((size_t)64*PSTR*2));  // [c][m]
  unsigned short* F16  = (unsigned short*)(ws + alloc((size_t)PSTR*64*2));  // [m][c]

  proj<<<dim3(43, 5, 3), 256, 0, stream>>>(X, WK, WQ, WV, part);
  reduce_proj<<<dim3(688, 3), 256, 0, stream>>>(part, K16, QT16, VT16);
  gemmG<<<dim3(43, 15), 256, 0, stream>>>(U, QT16, part);
  reduce_g<<<dim3(688), 256, 0, stream>>>(part, lm, G2T);
  gemmF<<<dim3(43, 15), 256, 0, stream>>>(U, G2T, part);
  reduce_f<<<dim3(680), 256, 0, stream>>>(part, F16);
  fused_attn<<<dim3((NV + 7)/8), 256, 0, stream>>>(F16, K16, A, VT16, (float*)d_out);
}

// Round 6
// 236.005 us; speedup vs baseline: 2.4000x; 1.1073x over previous
//
#include <hip/hip_runtime.h>

#define NV 2708
#define INC 1433
#define PSTR 2720          // padded row len for K16/VT16/F16 (mult of 32)
#define BSTR 2752          // padded row len for QT16/G2T16 (mult of 64)
#define SLAB ((size_t)(2752*64))

typedef __attribute__((ext_vector_type(8))) short bf16x8;
typedef __attribute__((ext_vector_type(4))) float f32x4;
typedef __attribute__((ext_vector_type(4))) unsigned short u16x4;

__device__ __forceinline__ float bf2f(unsigned short u){
  union { unsigned int i; float f; } v; v.i = ((unsigned int)u) << 16; return v.f;
}
__device__ __forceinline__ unsigned short f2bf(float f){
  union { float f; unsigned int i; } v; v.f = f;
  return (unsigned short)((v.i + 0x7fffu + ((v.i >> 16) & 1u)) >> 16);  // RNE
}

// =============== proj: partials of {K,Q,V} = X @ W^T, split-K ===============
// grid (43, 5, 3). Staging is WAVE-CONTIGUOUS: lane L reads col k0+L of one row
// per instruction (256B/instr, ~5 lines) instead of per-thread-contiguous
// chunks (64 lines/instr -> TA serialization, the round-5 81us pathology).
__global__ __launch_bounds__(256) void proj(
    const float* __restrict__ X, const float* __restrict__ W0,
    const float* __restrict__ W1, const float* __restrict__ W2,
    float* __restrict__ part)
{
  __shared__ __align__(16) unsigned short At[64*72];
  __shared__ __align__(16) unsigned short Bt[64*72];
  const int tid = threadIdx.x;
  const int lane = tid & 63, wave = tid >> 6, quad = lane >> 4, lr = lane & 15;
  const int m0 = blockIdx.x * 64;
  const int s  = blockIdx.y, z = blockIdx.z;
  const float* W = (z==0) ? W0 : (z==1) ? W1 : W2;
  const int kbeg = s * 320, kend = min(kbeg + 320, INC);
  const int wm = (wave & 1) * 32, wn = (wave >> 1) * 32;
  f32x4 acc[2][2] = {};

  for (int k0 = kbeg; k0 < kend; k0 += 64){
    const int kk = k0 + lane;
    const bool kok = kk < kend;
    #pragma unroll
    for (int e = 0; e < 16; e++){
      int row = e*4 + wave;
      float xv = 0.f, wv = 0.f;
      if (kok && (m0 + row) < NV) xv = X[(size_t)(m0+row)*INC + kk];
      if (kok)                    wv = W[(size_t)row*INC + kk];
      At[row*72 + lane] = f2bf(xv);
      Bt[row*72 + lane] = f2bf(wv);
    }
    __syncthreads();
    #pragma unroll
    for (int ks = 0; ks < 2; ks++){
      bf16x8 af[2], bv[2];
      #pragma unroll
      for (int t = 0; t < 2; t++){
        af[t] = *(const bf16x8*)&At[(wm + t*16 + lr)*72 + ks*32 + quad*8];
        bv[t] = *(const bf16x8*)&Bt[(wn + t*16 + lr)*72 + ks*32 + quad*8];
      }
      #pragma unroll
      for (int tm = 0; tm < 2; tm++)
        #pragma unroll
        for (int tn = 0; tn < 2; tn++)
          acc[tm][tn] = __builtin_amdgcn_mfma_f32_16x16x32_bf16(af[tm], bv[tn], acc[tm][tn], 0, 0, 0);
    }
    __syncthreads();
  }
  float* dst = part + (size_t)(z*5 + s) * SLAB;
  #pragma unroll
  for (int tm = 0; tm < 2; tm++)
    #pragma unroll
    for (int tn = 0; tn < 2; tn++)
      #pragma unroll
      for (int e = 0; e < 4; e++)
        dst[(size_t)(m0 + wm + tm*16 + quad*4 + e)*64 + wn + tn*16 + lr] = acc[tm][tn][e];
}

// K16[m][c] ; QT16[c][m] ; VT16[c][m]  (+zero pads). grid (688, 3).
// Scatter writes here are fine: total volume ~350KB, TA cost negligible.
__global__ __launch_bounds__(256) void reduce_proj(
    const float* __restrict__ part, unsigned short* __restrict__ K16,
    unsigned short* __restrict__ QT16, unsigned short* __restrict__ VT16)
{
  int idx = blockIdx.x*256 + threadIdx.x;       // < 2752*64
  int z = blockIdx.y;
  int m = idx >> 6, c = idx & 63;
  const float* base = part + (size_t)z*5*SLAB + idx;
  float v = 0.f;
  #pragma unroll
  for (int s = 0; s < 5; s++) v += base[s*SLAB];
  unsigned short h = (m < NV) ? f2bf(v) : (unsigned short)0;
  if (z == 0){ if (m < PSTR) K16[(size_t)m*64 + c] = h; }
  else if (z == 1){ QT16[(size_t)c*BSTR + m] = h; }
  else { if (m < PSTR) VT16[(size_t)c*PSTR + m] = h; }
}

// =============== gemmG: partials of G = U^T @ Q ==============================
// grid (43, 15). A[m][k] = U[k][m0+m]: staged from U ROWS (wave-contiguous,
// 256B aligned). B[c][k] from QT16 rows: unguarded b128 (padding zeros mask).
__global__ __launch_bounds__(256) void gemmG(
    const float* __restrict__ U, const unsigned short* __restrict__ QT,
    float* __restrict__ part)
{
  __shared__ __align__(16) unsigned short At[64*72];
  __shared__ __align__(16) unsigned short Bt[64*72];
  const int tid = threadIdx.x;
  const int lane = tid & 63, wave = tid >> 6, quad = lane >> 4, lr = lane & 15;
  const int m0 = blockIdx.x * 64;
  const int s  = blockIdx.y;
  const int kbeg = s * 192, kend = min(kbeg + 192, NV);
  const int wm = (wave & 1) * 32, wn = (wave >> 1) * 32;
  f32x4 acc[2][2] = {};

  const bool mok = (m0 + lane) < NV;
  const int bc = tid >> 2, bseg = tid & 3;

  for (int k0 = kbeg; k0 < kend; k0 += 64){
    #pragma unroll
    for (int e = 0; e < 16; e++){
      int klocal = e*4 + wave;
      int krow = k0 + klocal;
      float v = 0.f;
      if (krow < kend && mok) v = U[(size_t)krow*NV + m0 + lane];
      At[lane*72 + klocal] = f2bf(v);
    }
    {
      const unsigned short* q = QT + (size_t)bc*BSTR + k0 + bseg*16;
      *(bf16x8*)&Bt[bc*72 + bseg*16]     = *(const bf16x8*)(q);
      *(bf16x8*)&Bt[bc*72 + bseg*16 + 8] = *(const bf16x8*)(q + 8);
    }
    __syncthreads();
    #pragma unroll
    for (int ks = 0; ks < 2; ks++){
      bf16x8 af[2], bv[2];
      #pragma unroll
      for (int t = 0; t < 2; t++){
        af[t] = *(const bf16x8*)&At[(wm + t*16 + lr)*72 + ks*32 + quad*8];
        bv[t] = *(const bf16x8*)&Bt[(wn + t*16 + lr)*72 + ks*32 + quad*8];
      }
      #pragma unroll
      for (int tm = 0; tm < 2; tm++)
        #pragma unroll
        for (int tn = 0; tn < 2; tn++)
          acc[tm][tn] = __builtin_amdgcn_mfma_f32_16x16x32_bf16(af[tm], bv[tn], acc[tm][tn], 0, 0, 0);
    }
    __syncthreads();
  }
  float* dst = part + (size_t)s * SLAB;
  #pragma unroll
  for (int tm = 0; tm < 2; tm++)
    #pragma unroll
    for (int tn = 0; tn < 2; tn++)
      #pragma unroll
      for (int e = 0; e < 4; e++)
        dst[(size_t)(m0 + wm + tm*16 + quad*4 + e)*64 + wn + tn*16 + lr] = acc[tm][tn][e];
}

// G2T16[c][m] = bf16(G[m][c] * lmbd[m]/64), zero pads. grid 688.
__global__ __launch_bounds__(256) void reduce_g(
    const float* __restrict__ part, const float* __restrict__ lm,
    unsigned short* __restrict__ G2T)
{
  int idx = blockIdx.x*256 + threadIdx.x;
  int m = idx >> 6, c = idx & 63;
  const float* base = part + idx;
  float v = 0.f;
  #pragma unroll
  for (int s = 0; s < 15; s++) v += base[s*SLAB];
  unsigned short h = 0;
  if (m < NV) h = f2bf(v * lm[m] * (1.0f/64.0f));
  G2T[(size_t)c*BSTR + m] = h;
}

// =============== gemmF: partials of F = U @ G2 ==============================
// U rows are 16B-aligned (2708*4=10832%16==0): float4, 1KB/instr, 4 instrs/iter.
__global__ __launch_bounds__(256) void gemmF(
    const float* __restrict__ U, const unsigned short* __restrict__ G2T,
    float* __restrict__ part)
{
  __shared__ __align__(16) unsigned short At[64*72];
  __shared__ __align__(16) unsigned short Bt[64*72];
  const int tid = threadIdx.x;
  const int lane = tid & 63, wave = tid >> 6, quad = lane >> 4, lr = lane & 15;
  const int m0 = blockIdx.x * 64;
  const int s  = blockIdx.y;
  const int kbeg = s * 192, kend = min(kbeg + 192, NV);
  const int wm = (wave & 1) * 32, wn = (wave >> 1) * 32;
  f32x4 acc[2][2] = {};

  const int bc = tid >> 2, bseg = tid & 3;

  for (int k0 = kbeg; k0 < kend; k0 += 64){
    #pragma unroll
    for (int e = 0; e < 4; e++){
      int row = e*16 + wave*4 + (lane >> 4);       // 0..63, each exactly once
      int col = k0 + (lane & 15)*4;
      float4 v = make_float4(0.f,0.f,0.f,0.f);
      if ((m0 + row) < NV && col + 4 <= kend)      // kend%4==0: no straddle
        v = *(const float4*)(U + (size_t)(m0+row)*NV + col);
      u16x4 h = { f2bf(v.x), f2bf(v.y), f2bf(v.z), f2bf(v.w) };
      *(u16x4*)&At[row*72 + (lane & 15)*4] = h;
    }
    {
      const unsigned short* g = G2T + (size_t)bc*BSTR + k0 + bseg*16;
      *(bf16x8*)&Bt[bc*72 + bseg*16]     = *(const bf16x8*)(g);
      *(bf16x8*)&Bt[bc*72 + bseg*16 + 8] = *(const bf16x8*)(g + 8);
    }
    __syncthreads();
    #pragma unroll
    for (int ks = 0; ks < 2; ks++){
      bf16x8 af[2], bv[2];
      #pragma unroll
      for (int t = 0; t < 2; t++){
        af[t] = *(const bf16x8*)&At[(wm + t*16 + lr)*72 + ks*32 + quad*8];
        bv[t] = *(const bf16x8*)&Bt[(wn + t*16 + lr)*72 + ks*32 + quad*8];
      }
      #pragma unroll
      for (int tm = 0; tm < 2; tm++)
        #pragma unroll
        for (int tn = 0; tn < 2; tn++)
          acc[tm][tn] = __builtin_amdgcn_mfma_f32_16x16x32_bf16(af[tm], bv[tn], acc[tm][tn], 0, 0, 0);
    }
    __syncthreads();
  }
  float* dst = part + (size_t)s * SLAB;
  #pragma unroll
  for (int tm = 0; tm < 2; tm++)
    #pragma unroll
    for (int tn = 0; tn < 2; tn++)
      #pragma unroll
      for (int e = 0; e < 4; e++)
        dst[(size_t)(m0 + wm + tm*16 + quad*4 + e)*64 + wn + tn*16 + lr] = acc[tm][tn][e];
}

// F16[m][c] (rows padded to 2720, pads zero). grid 680.
__global__ __launch_bounds__(256) void reduce_f(
    const float* __restrict__ part, unsigned short* __restrict__ F16)
{
  int idx = blockIdx.x*256 + threadIdx.x;       // < 2720*64
  int m = idx >> 6, c = idx & 63;
  const float* base = part + (size_t)m*64 + c;
  float v = 0.f;
  #pragma unroll
  for (int s = 0; s < 15; s++) v += base[s*SLAB];
  F16[(size_t)m*64 + c] = (m < NV) ? f2bf(v) : (unsigned short)0;
}

// =============== fused |F K^T| -> masked softmax -> P V =====================
__device__ __forceinline__ float blockReduceMax(float v, float* red){
  #pragma unroll
  for (int o = 32; o; o >>= 1) v = fmaxf(v, __shfl_xor(v, o, 64));
  __syncthreads();
  if ((threadIdx.x & 63) == 0) red[threadIdx.x >> 6] = v;
  __syncthreads();
  return fmaxf(fmaxf(red[0], red[1]), fmaxf(red[2], red[3]));
}
__device__ __forceinline__ float blockReduceSum(float v, float* red){
  #pragma unroll
  for (int o = 32; o; o >>= 1) v += __shfl_xor(v, o, 64);
  __syncthreads();
  if ((threadIdx.x & 63) == 0) red[threadIdx.x >> 6] = v;
  __syncthreads();
  return red[0] + red[1] + red[2] + red[3];
}

__global__ __launch_bounds__(256) void fused_attn(
    const unsigned short* __restrict__ F16, const unsigned short* __restrict__ K16,
    const int* __restrict__ Amask, const unsigned short* __restrict__ VT,
    float* __restrict__ Hout)
{
  __shared__ __align__(16) unsigned short pbuf[8*PSTR];
  __shared__ float red[4];
  __shared__ float rinv[8];
  const int tid  = threadIdx.x;
  const int lane = tid & 63, wave = tid >> 6;
  const int quad = lane >> 4, lr = lane & 15;
  const int i0 = blockIdx.x * 8;
  const int NT = (NV + 15) / 16;   // 170

  // ---- phase A: |F K^T| rows -> pbuf (bf16) ----
  const unsigned short* frow = F16 + (size_t)(i0 + (lr & 7))*64;
  bf16x8 af0 = *(const bf16x8*)(frow + quad*8);
  bf16x8 af1 = *(const bf16x8*)(frow + 32 + quad*8);
  for (int t = wave; t < NT; t += 4){
    int n0 = t*16;
    const unsigned short* krow = K16 + (size_t)(n0 + lr)*64;
    bf16x8 b0 = *(const bf16x8*)(krow + quad*8);
    bf16x8 b1 = *(const bf16x8*)(krow + 32 + quad*8);
    f32x4 sv = {};
    sv = __builtin_amdgcn_mfma_f32_16x16x32_bf16(af0, b0, sv, 0, 0, 0);
    sv = __builtin_amdgcn_mfma_f32_16x16x32_bf16(af1, b1, sv, 0, 0, 0);
    if (quad < 2){
      int col = n0 + lr;
      if (col < NV){
        #pragma unroll
        for (int e = 0; e < 4; e++)
          pbuf[(size_t)(quad*4 + e)*PSTR + col] = f2bf(fabsf(sv[e]));
      }
    }
  }
  __syncthreads();

  if (tid < PSTR - NV){
    #pragma unroll
    for (int rr = 0; rr < 8; rr++) pbuf[rr*PSTR + NV + tid] = 0;
  }

  // ---- phase B: masked softmax per row (int4 mask, ushort4 pbuf) ----
  for (int rr = 0; rr < 8; rr++){
    const int i = i0 + rr;
    float ev[12]; int mk[12];
    float mx = -1e30f;
    if (i < NV){
      const int4* arow = (const int4*)(Amask + (size_t)i*NV);
      #pragma unroll
      for (int s = 0; s < 3; s++){
        int c = tid + s*256;
        int4 a = {0,0,0,0};
        u16x4 e4 = {0,0,0,0};
        if (c < NV/4){ a = arow[c]; e4 = *(const u16x4*)&pbuf[rr*PSTR + 4*c]; }
        mk[s*4+0] = a.x; mk[s*4+1] = a.y; mk[s*4+2] = a.z; mk[s*4+3] = a.w;
        #pragma unroll
        for (int e = 0; e < 4; e++){
          ev[s*4+e] = bf2f(e4[e]);
          if (mk[s*4+e]) mx = fmaxf(mx, ev[s*4+e]);
        }
      }
    } else {
      #pragma unroll
      for (int q = 0; q < 12; q++){ ev[q] = 0.f; mk[q] = 0; }
    }
    mx = blockReduceMax(mx, red);
    float sum = 0.f;
    #pragma unroll
    for (int s = 0; s < 3; s++){
      int c = tid + s*256;
      if (c < NV/4){
        u16x4 pw;
        #pragma unroll
        for (int e = 0; e < 4; e++){
          float p = 0.f;
          if (i < NV && mk[s*4+e]) p = __expf(ev[s*4+e] - mx);
          sum += p;
          pw[e] = f2bf(p);
        }
        *(u16x4*)&pbuf[rr*PSTR + 4*c] = pw;
      }
    }
    sum = blockReduceSum(sum, red);
    if (tid == 0) rinv[rr] = (sum > 0.f) ? (1.f/sum) : 0.f;
  }
  __syncthreads();

  // ---- phase C: H = (P V) * rinv ----
  const int c0 = wave * 16;
  const int mr = lr & 7;
  f32x4 acc = {0.f, 0.f, 0.f, 0.f};
  for (int k0 = 0; k0 < NV; k0 += 32){
    bf16x8 af = *(const bf16x8*)&pbuf[(size_t)mr*PSTR + k0 + quad*8];
    bf16x8 bv = *(const bf16x8*)&VT[(size_t)(c0 + lr)*PSTR + k0 + quad*8];
    acc = __builtin_amdgcn_mfma_f32_16x16x32_bf16(af, bv, acc, 0, 0, 0);
  }
  #pragma unroll
  for (int e = 0; e < 4; e++){
    int row = quad*4 + e;
    if (row < 8){
      int i = i0 + row;
      if (i < NV) Hout[(size_t)i*64 + c0 + lr] = acc[e] * rinv[row];
    }
  }
}

extern "C" void kernel_launch(void* const* d_in, const int* in_sizes, int n_in,
                              void* d_out, int out_size, void* d_ws, size_t ws_size,
                              hipStream_t stream){
  (void)in_sizes; (void)n_in; (void)out_size; (void)ws_size;
  const float* X  = (const float*)d_in[0];
  const int*   A  = (const int*)d_in[1];
  const float* U  = (const float*)d_in[2];
  const float* WK = (const float*)d_in[3];
  const float* WQ = (const float*)d_in[4];
  const float* WV = (const float*)d_in[5];
  const float* lm = (const float*)d_in[6];

  char* ws = (char*)d_ws;
  size_t off = 0;
  auto alloc = [&](size_t bytes){ size_t o = off; off = (off + bytes + 255) & ~(size_t)255; return o; };
  float*          part = (float*)(ws + alloc(15*SLAB*4));                   // 10.6 MB, reused 3x
  unsigned short* K16  = (unsigned short*)(ws + alloc((size_t)PSTR*64*2));  // [m][c]
  unsigned short* QT16 = (unsigned short*)(ws + alloc((size_t)64*BSTR*2));  // [c][m]
  unsigned short* G2T  = (unsigned short*)(ws + alloc((size_t)64*BSTR*2));  // [c][m]
  unsigned short* VT16 = (unsigned short*)(ws + alloc((size_t)64*PSTR*2));  // [c][m]
  unsigned short* F16  = (unsigned short*)(ws + alloc((size_t)PSTR*64*2));  // [m][c]

  proj<<<dim3(43, 5, 3), 256, 0, stream>>>(X, WK, WQ, WV, part);
  reduce_proj<<<dim3(688, 3), 256, 0, stream>>>(part, K16, QT16, VT16);
  gemmG<<<dim3(43, 15), 256, 0, stream>>>(U, QT16, part);
  reduce_g<<<dim3(688), 256, 0, stream>>>(part, lm, G2T);
  gemmF<<<dim3(43, 15), 256, 0, stream>>>(U, G2T, part);
  reduce_f<<<dim3(680), 256, 0, stream>>>(part, F16);
  fused_attn<<<dim3((NV + 7)/8), 256, 0, stream>>>(F16, K16, A, VT16, (float*)d_out);
}